// Round 4
// baseline (113.492 us; speedup 1.0000x reference)
//
#include <hip/hip_runtime.h>

#define NF    50000
#define PADP  50001
#define KN    9
#define KTOT  2304
#define NCHUNK 782
#define NT    72          // 2304 / 32  (BK=32 K-tiles)
#define BM    224
#define NBLK  224         // 1 block/CU, 224*224 = 50176 >= 50000

// ---- ws layout (bytes) ----
#define WT_OFF   0u          // 256*2304*2 = 1179648
#define FLAG_OFF 1179648u    // 4
#define CNT_OFF  1179904u    // 782*4
#define IDX_OFF  1183744u    // 450000*4
#define PADX_OFF 2983744u    // 50001*256*2

typedef float f32x4 __attribute__((ext_vector_type(4)));
typedef __bf16 bf16x8 __attribute__((ext_vector_type(8)));

typedef const __attribute__((address_space(1))) unsigned int* gas_t;
typedef __attribute__((address_space(3))) unsigned int* las_t;

static __device__ __forceinline__ void gll16(const void* g, void* l) {
  __builtin_amdgcn_global_load_lds((gas_t)g, (las_t)l, 16, 0, 0);
}

static __device__ __forceinline__ unsigned short f2bf(float f) {
  unsigned int u = __builtin_bit_cast(unsigned int, f);
  u = u + 0x7fffu + ((u >> 16) & 1u);      // RNE
  return (unsigned short)(u >> 16);
}

// ---------- preprocessing ----------

__global__ void k_pre1(const unsigned char* __restrict__ pad, int* __restrict__ cnt,
                       const unsigned int* __restrict__ raw, int* __restrict__ flag) {
  int t = blockIdx.x * 256 + threadIdx.x;
  bool ip = (t < PADP) ? (pad[t] != 0) : true;
  unsigned long long m = __ballot(ip);
  int c = t >> 6;
  if ((threadIdx.x & 63) == 0 && c < NCHUNK) cnt[c] = __popcll(m);
  if (blockIdx.x == 0 && threadIdx.x < 64) {
    unsigned int v = raw[threadIdx.x * 2 + 1];
    unsigned long long nz = __ballot(v != 0u);
    if (threadIdx.x == 0) flag[0] = (nz == 0ull) ? 1 : 0;
  }
}

__global__ void k_wt(const float* __restrict__ w, unsigned short* __restrict__ wt) {
  int o = blockIdx.x;
  int i = threadIdx.x;
  const float* wr = w + (o * 256 + i) * 9;
  float wv[9];
  float s = 0.f;
#pragma unroll
  for (int k = 0; k < 9; ++k) { wv[k] = wr[k]; s += wv[k] * wv[k]; }
#pragma unroll
  for (int d = 32; d >= 1; d >>= 1) s += __shfl_xor(s, d);
  __shared__ float red[4];
  if ((i & 63) == 0) red[i >> 6] = s;
  __syncthreads();
  float dc = rsqrtf(red[0] + red[1] + red[2] + red[3] + 1e-8f);
#pragma unroll
  for (int k = 0; k < 9; ++k)
    wt[o * KTOT + k * 256 + i] = f2bf(wv[k] * dc);
}

// rank -> padded_x bf16 conversion + int64->int32 neighborhood conversion.
__global__ __launch_bounds__(256) void k_rankpadx(
    const float* __restrict__ x, const unsigned char* __restrict__ pad,
    const int* __restrict__ cnt, unsigned short* __restrict__ padx,
    const void* __restrict__ nbr, const int* __restrict__ flag,
    int* __restrict__ idx32) {
  const int b = blockIdx.x;
  const int tid = threadIdx.x, w = tid >> 6, lane = tid & 63;
  const int p0 = b * 256;
  int s = 0;
  for (int i = tid; i < b * 4; i += 256) s += cnt[i];
#pragma unroll
  for (int d = 32; d >= 1; d >>= 1) s += __shfl_xor(s, d);
  __shared__ int ws4[4], wpads[4], rnk[256];
  int p = p0 + w * 64 + lane;
  bool ip = (p < PADP) ? (pad[p] != 0) : true;
  unsigned long long m = __ballot(ip);
  if (lane == 0) { ws4[w] = s; wpads[w] = __popcll(m); }
  __syncthreads();
  int base_pads = ws4[0] + ws4[1] + ws4[2] + ws4[3];
  int wbefore = 0;
#pragma unroll
  for (int i = 0; i < 4; ++i) if (i < w) wbefore += wpads[i];
  int before = __popcll(m & ((1ull << lane) - 1ull));
  rnk[w * 64 + lane] = ip ? -1 : (p - (base_pads + wbefore + before));
  __syncthreads();
  const int c = lane * 4;
  for (int i = 0; i < 64; ++i) {
    int rl = i * 4 + w;
    int pp = p0 + rl;
    if (pp >= PADP) continue;
    int rr = rnk[rl];
    ushort4 ov;
    if (rr < 0) { ov.x = 0; ov.y = 0; ov.z = 0; ov.w = 0; }
    else {
      const float4 v = *(const float4*)(x + rr * 256 + c);
      ov.x = f2bf(v.x); ov.y = f2bf(v.y); ov.z = f2bf(v.z); ov.w = f2bf(v.w);
    }
    *(ushort4*)(padx + pp * 256 + c) = ov;
  }
  const bool f64 = (flag[0] != 0);
  const long long* n64 = (const long long*)nbr;
  const int* n32 = (const int*)nbr;
  for (int e = b * 256 + tid; e < NF * KN; e += 196 * 256)
    idx32[e] = f64 ? (int)n64[e] : n32[e];
}

// ---------- main gathered GEMM ----------
// BM=224 (staged 256 rows) x BN=256 x BK=32, 512 thr (8 waves, 2M x 4N).
// LDS ring of 4 x 32KB (A 256x64B + B 256x64B), lead-3, counted vmcnt(12).
// Staging: lane-LINEAR dest (uniform base + 16*lane), swizzle on SOURCE side:
//   LDS slot s of row r holds global slot s ^ ((r>>1)&3); reads use matching XOR.
__global__ __launch_bounds__(512, 2) void k_main(
    const unsigned short* __restrict__ padx,   // [50001][256] bf16
    const unsigned short* __restrict__ wt,     // [256][2304] bf16
    const int* __restrict__ idx32,             // [50000][9]
    const float* __restrict__ bias,            // [256]
    float* __restrict__ out) {                 // [50000][256] f32
  __shared__ __align__(16) unsigned char sm[140288];
  const int tid = threadIdx.x;
  const int wv = tid >> 6, lane = tid & 63;
  const int m0 = blockIdx.x * BM;
  int* idx_lds = (int*)(sm + 131072);

  // ---- prologue: idx cache (256 staged rows x 9 neighbors) ----
  for (int e = tid; e < 2304; e += 512) {
    int f = m0 + e / 9;
    int nb = e - (e / 9) * 9;
    if (f >= NF) f = NF - 1;
    idx_lds[e] = idx32[f * KN + nb];
  }
  __syncthreads();

  // ---- staging setup: per instr, wave covers 16 rows x 64B, lane-linear ----
  const int r0 = wv * 32 + (lane >> 2);          // rows for instr j=0
  const int r1 = r0 + 16;                        // instr j=1
  const int srcsl = ((lane & 3) ^ ((lane >> 3) & 3)) * 8;  // element offset
  const unsigned short* wtb0 = wt + r0 * KTOT + srcsl;
  const unsigned short* wtb1 = wt + r1 * KTOT + srcsl;
  const int aD0 = wv * 2048, aD1 = aD0 + 1024;   // uniform LDS bases (A)
  const int bD0 = 16384 + aD0, bD1 = bD0 + 1024; // (B)

#define STAGE(u, p0_, p1_) {                                 \
    const int c0_ = ((u) & 7) * 32;                          \
    unsigned char* bb_ = sm + ((u) & 3) * 32768;             \
    gll16(padx + (p0_) * 256 + c0_ + srcsl, bb_ + aD0);      \
    gll16(padx + (p1_) * 256 + c0_ + srcsl, bb_ + aD1);      \
    gll16(wtb0 + (u) * 32, bb_ + bD0);                       \
    gll16(wtb1 + (u) * 32, bb_ + bD1); }

  // ---- fragment read setup ----
  const int q = lane & 15, hi = lane >> 4;
  const int wm = wv >> 2, wn = wv & 3;
  const int slotb = (hi ^ ((q >> 1) & 3)) * 16;
  int aoff[7], boff[4];
#pragma unroll
  for (int mi = 0; mi < 7; ++mi) aoff[mi] = (wm * 112 + mi * 16 + q) * 64 + slotb;
#pragma unroll
  for (int ni = 0; ni < 4; ++ni) boff[ni] = 16384 + (wn * 64 + ni * 16 + q) * 64 + slotb;

  f32x4 acc[7][4];
#pragma unroll
  for (int a = 0; a < 7; ++a)
#pragma unroll
    for (int b = 0; b < 4; ++b) {
      acc[a][b][0] = 0.f; acc[a][b][1] = 0.f; acc[a][b][2] = 0.f; acc[a][b][3] = 0.f;
    }

  // ---- prologue staging: tiles 0,1,2 (all neighbor 0) ----
  int pc0 = idx_lds[r0 * 9 + 0], pc1 = idx_lds[r1 * 9 + 0];
  int pn0 = idx_lds[r0 * 9 + 1], pn1 = idx_lds[r1 * 9 + 1];
  int pn20 = pn0, pn21 = pn1;
  STAGE(0, pc0, pc1); STAGE(1, pc0, pc1); STAGE(2, pc0, pc1);

  // ---- main loop: 9 neighbor groups x 8 K-subtiles (t = g*8+j, u = t+3) ----
  for (int g = 0; g < 9; ++g) {
#pragma unroll
    for (int j = 0; j < 8; ++j) {
      const int t = g * 8 + j;
      const int u = t + 3;
      {
        const int ps0 = (j <= 4) ? pc0 : pn0;
        const int ps1 = (j <= 4) ? pc1 : pn1;
        const int pu0 = (u < NT) ? ps0 : 0;
        const int pu1 = (u < NT) ? ps1 : 0;
        STAGE(u, pu0, pu1);
      }
      if (j == 0) {
        const int gn = (g + 2 > 8) ? 8 : (g + 2);
        pn20 = idx_lds[r0 * 9 + gn];
        pn21 = idx_lds[r1 * 9 + gn];
      }
      // tile t ready: drain own 4 oldest loads, then rendezvous
      asm volatile("s_waitcnt vmcnt(12)" ::: "memory");
      __builtin_amdgcn_s_barrier();
      __builtin_amdgcn_sched_barrier(0);
      const unsigned char* bb = sm + (t & 3) * 32768;
      bf16x8 bfr[4];
#pragma unroll
      for (int ni = 0; ni < 4; ++ni) bfr[ni] = *(const bf16x8*)(bb + boff[ni]);
      __builtin_amdgcn_s_setprio(1);
#pragma unroll
      for (int mi = 0; mi < 7; ++mi) {
        bf16x8 af = *(const bf16x8*)(bb + aoff[mi]);
#pragma unroll
        for (int ni = 0; ni < 4; ++ni)
          acc[mi][ni] = __builtin_amdgcn_mfma_f32_16x16x32_bf16(af, bfr[ni], acc[mi][ni], 0, 0, 0);
      }
      __builtin_amdgcn_s_setprio(0);
      // all reads of buf[t&3] done before next iter stages tile t+4 into it
      asm volatile("s_waitcnt lgkmcnt(0)" ::: "memory");
      __builtin_amdgcn_sched_barrier(0);
      __builtin_amdgcn_s_barrier();
      if (j == 7) { pc0 = pn0; pc1 = pn1; pn0 = pn20; pn1 = pn21; }
    }
  }
  asm volatile("s_waitcnt vmcnt(0)" ::: "memory");

  // ---- epilogue: bias + store ----
#pragma unroll
  for (int ni = 0; ni < 4; ++ni) {
    const int col = wn * 64 + ni * 16 + q;
    const float bv = bias[col];
#pragma unroll
    for (int mi = 0; mi < 7; ++mi) {
#pragma unroll
      for (int rr = 0; rr < 4; ++rr) {
        const int row = m0 + wm * 112 + mi * 16 + hi * 4 + rr;
        if (row < NF) out[row * 256 + col] = acc[mi][ni][rr] + bv;
      }
    }
  }
#undef STAGE
}

extern "C" void kernel_launch(void* const* d_in, const int* in_sizes, int n_in,
                              void* d_out, int out_size, void* d_ws, size_t ws_size,
                              hipStream_t stream) {
  const float* x = (const float*)d_in[0];
  const float* wfull = (const float*)d_in[1];
  const float* bias = (const float*)d_in[2];
  const void* nbr = d_in[3];
  const unsigned char* pad = (const unsigned char*)d_in[4];
  float* out = (float*)d_out;
  char* ws = (char*)d_ws;

  unsigned short* wt   = (unsigned short*)(ws + WT_OFF);
  int* flag            = (int*)(ws + FLAG_OFF);
  int* cnt             = (int*)(ws + CNT_OFF);
  int* idx32           = (int*)(ws + IDX_OFF);
  unsigned short* padx = (unsigned short*)(ws + PADX_OFF);

  k_pre1<<<196, 256, 0, stream>>>(pad, cnt, (const unsigned int*)nbr, flag);
  k_wt<<<256, 256, 0, stream>>>(wfull, wt);
  k_rankpadx<<<196, 256, 0, stream>>>(x, pad, cnt, padx, nbr, flag, idx32);
  k_main<<<NBLK, 512, 0, stream>>>(padx, wt, idx32, bias, out);
}